// Round 4
// baseline (391.414 us; speedup 1.0000x reference)
//
#include <hip/hip_runtime.h>

#define SN 6400      // H*W
#define CN 256       // channels (= GEMM K)
#define NBATCH 2
#define NTILES 50    // SN / 128
#define NCHUNK 10    // tile chunks per pass (grid = 50*10*2 = 1000 blocks ~ 4/CU)
#define TPC 5        // tiles per chunk

typedef _Float16 f16;
typedef f16 f16x8 __attribute__((ext_vector_type(8)));
typedef f16 f16x4 __attribute__((ext_vector_type(4)));
typedef float f32x4 __attribute__((ext_vector_type(4)));

__device__ __forceinline__ void gld16(const f16* g, f16* l) {
    __builtin_amdgcn_global_load_lds(
        (__attribute__((address_space(1))) void*)(g),
        (__attribute__((address_space(3))) void*)(l), 16, 0, 0);
}

// Stage a 128-row x 64-half (16 KB) K-chunk into LDS.
// LDS row = 64 halfs = 128 B = 8 x 16B chunks. Chunk at LDS position c holds
// global chunk c ^ (row&7) (swizzle on the SOURCE address; DMA lane->LDS map
// is fixed: wave-uniform base + lane*16B). Verified conflict-free (R2: 0).
__device__ __forceinline__ void stage64(const f16* __restrict__ gbase,
                                        f16* lbase, int tid) {
    #pragma unroll
    for (int it = 0; it < 4; ++it) {
        int q = it * 256 + tid;
        int row = q >> 3, c = q & 7;
        int cg = c ^ (row & 7);
        gld16(gbase + (size_t)row * CN + cg * 8,
              lbase + (size_t)(q & ~63) * 8);
    }
}

// ---------------- prep kernels ----------------

__global__ __launch_bounds__(256) void k_meanT(const float* __restrict__ T,
                                               float* __restrict__ meanT) {
    int c = blockIdx.x, t = threadIdx.x;
    const float* p0 = T + (size_t)c * SN;
    const float* p1 = T + (size_t)(CN + c) * SN;
    float s = 0.f;
    for (int i = t; i < SN; i += 256) s += p0[i] + p1[i];
    #pragma unroll
    for (int d = 1; d < 64; d <<= 1) s += __shfl_xor(s, d, 64);
    __shared__ float sb[4];
    if ((t & 63) == 0) sb[t >> 6] = s;
    __syncthreads();
    if (t == 0) meanT[c] = (sb[0] + sb[1] + sb[2] + sb[3]) * (1.0f / 12800.0f);
}

// transpose [n,c,s] -> [n,s,c], center, cast to fp16 (normalized by k_nrm)
__global__ __launch_bounds__(256) void k_xpose(const float* __restrict__ X,
                                               const float* __restrict__ meanT,
                                               f16* __restrict__ out) {
    int n = blockIdx.z, c0 = blockIdx.y * 32, s0 = blockIdx.x * 64;
    __shared__ float tile[32][65];
    int tx = threadIdx.x & 63, ty = threadIdx.x >> 6;
    const float* Xb = X + ((size_t)n * CN + c0) * SN + s0;
    #pragma unroll
    for (int cy = ty; cy < 32; cy += 4)
        tile[cy][tx] = Xb[(size_t)cy * SN + tx] - meanT[c0 + cy];
    __syncthreads();
    int cc = threadIdx.x & 31, sy = threadIdx.x >> 5;
    f16* ob = out + ((size_t)n * SN + s0) * CN + c0;
    #pragma unroll
    for (int sr = sy; sr < 64; sr += 8)
        ob[(size_t)sr * CN + cc] = (f16)tile[cc][sr];
}

// fused: per-row sum-of-squares -> rsqrt -> in-place scale (one wave per row,
// row lives in registers; does BOTH arrays to amortize launch cost)
__global__ __launch_bounds__(256) void k_nrm(f16* __restrict__ Ah,
                                             f16* __restrict__ Bh) {
    int w = threadIdx.x >> 6, lane = threadIdx.x & 63;
    int idx = blockIdx.x * 4 + w;
    f16x4* pa = (f16x4*)(Ah + (size_t)idx * CN + lane * 4);
    f16x4* pb = (f16x4*)(Bh + (size_t)idx * CN + lane * 4);
    f16x4 a = *pa, b = *pb;
    float sa = 0.f, sb = 0.f;
    #pragma unroll
    for (int j = 0; j < 4; ++j) {
        float x = (float)a[j]; sa += x * x;
        float y = (float)b[j]; sb += y * y;
    }
    #pragma unroll
    for (int d = 1; d < 64; d <<= 1) {
        sa += __shfl_xor(sa, d, 64);
        sb += __shfl_xor(sb, d, 64);
    }
    float ra = rsqrtf(sa), rb = rsqrtf(sb);
    #pragma unroll
    for (int j = 0; j < 4; ++j) {
        a[j] = (f16)((float)a[j] * ra);
        b[j] = (f16)((float)b[j] * rb);
    }
    *pa = a; *pb = b;
}

// ---------------- fused GEMM passes (m97-shape: A and B both LDS-staged) ----
// Fixed tile = MFMA A operand (rows of output); loop tiles = B operand (cols).
// PASS 0: per-row max of cos                          (fixed = I rows i)
// PASS 1: per-row sum of exp((10 - g_i*raw)/ln2)      (fixed = I rows i)
// PASS 2: per-row max over cols of (alpha_c - g_c*raw)(fixed = T rows j)
template <int PASS>
__global__ __launch_bounds__(256, 3) void k_gemm(const f16* __restrict__ A,
                                                 const f16* __restrict__ B,
                                                 const float* __restrict__ grow,
                                                 const float* __restrict__ alpha,
                                                 float* __restrict__ outP) {
    const int n = blockIdx.z, chunk = blockIdx.y, ft = blockIdx.x;
    const int tid = threadIdx.x, lane = tid & 63, wv = tid >> 6;
    const int wr = wv >> 1, wc = wv & 1, quad = lane >> 4, lrow = lane & 15;

    __shared__ f16 Ab[128 * 64];    // 16 KB
    __shared__ f16 Bb[128 * 64];    // 16 KB

    const f16* At = A + ((size_t)n * SN + (size_t)ft * 128) * CN;
    const f16* Lnb = B + (size_t)n * SN * CN;

    // per-lane LDS read offsets (halfs), conflict-free via XOR swizzle
    int offA[4][2], offB[4][2];
    #pragma unroll
    for (int mt = 0; mt < 4; ++mt) {
        int ra = wr * 64 + mt * 16 + lrow;
        int rb = wc * 64 + mt * 16 + lrow;
        #pragma unroll
        for (int kk = 0; kk < 2; ++kk) {
            offA[mt][kk] = ra * 64 + (((kk * 4 + quad) ^ (ra & 7)) * 8);
            offB[mt][kk] = rb * 64 + (((kk * 4 + quad) ^ (rb & 7)) * 8);
        }
    }

    // PASS1 per-row exp coefficients (rows fixed for whole block)
    const float L2E = 1.44269504089f;
    float a0c[4][4], a1c[4][4];
    if constexpr (PASS == 1) {
        #pragma unroll
        for (int mt = 0; mt < 4; ++mt)
            #pragma unroll
            for (int v = 0; v < 4; ++v) {
                int r = ft * 128 + wr * 64 + mt * 16 + quad * 4 + v;
                float gg = grow[(size_t)n * SN + r];
                a1c[mt][v] = 0.5f * gg * L2E;
                a0c[mt][v] = (10.f - 0.5f * gg) * L2E;
            }
    }

    float runRow[4][4];
    #pragma unroll
    for (int mt = 0; mt < 4; ++mt)
        #pragma unroll
        for (int v = 0; v < 4; ++v) runRow[mt][v] = (PASS == 1) ? 0.f : -3.0e38f;

    float gl4[4], al4[4];

    for (int t = 0; t < TPC; ++t) {
        const f16* Lt = Lnb + (size_t)(chunk * TPC + t) * 128 * CN;

        if constexpr (PASS == 2) {
            #pragma unroll
            for (int nt = 0; nt < 4; ++nt) {
                int i = (chunk * TPC + t) * 128 + wc * 64 + nt * 16 + lrow;
                gl4[nt] = grow[(size_t)n * SN + i];
                al4[nt] = alpha[(size_t)n * SN + i];
            }
        }

        f32x4 acc[4][4];
        #pragma unroll
        for (int mt = 0; mt < 4; ++mt)
            #pragma unroll
            for (int nt = 0; nt < 4; ++nt) acc[mt][nt] = (f32x4){0.f, 0.f, 0.f, 0.f};

        #pragma unroll 1
        for (int h = 0; h < 4; ++h) {
            __syncthreads();                      // prev-stage reads complete
            stage64(At + h * 64, Ab, tid);
            stage64(Lt + h * 64, Bb, tid);
            __syncthreads();                      // DMA landed (vmcnt drain)
            #pragma unroll
            for (int kk = 0; kk < 2; ++kk) {
                f16x8 af[4], bf[4];
                #pragma unroll
                for (int mt = 0; mt < 4; ++mt) af[mt] = *(const f16x8*)&Ab[offA[mt][kk]];
                #pragma unroll
                for (int nt = 0; nt < 4; ++nt) bf[nt] = *(const f16x8*)&Bb[offB[nt][kk]];
                #pragma unroll
                for (int mt = 0; mt < 4; ++mt)
                    #pragma unroll
                    for (int nt = 0; nt < 4; ++nt)
                        acc[mt][nt] = __builtin_amdgcn_mfma_f32_16x16x32_f16(
                            af[mt], bf[nt], acc[mt][nt], 0, 0, 0);
            }
        }

        // ---- per-tile epilogue (registers only) ----
        if constexpr (PASS == 0) {
            #pragma unroll
            for (int mt = 0; mt < 4; ++mt)
                #pragma unroll
                for (int v = 0; v < 4; ++v) {
                    float m = fmaxf(fmaxf(acc[mt][0][v], acc[mt][1][v]),
                                    fmaxf(acc[mt][2][v], acc[mt][3][v]));
                    runRow[mt][v] = fmaxf(runRow[mt][v], m);
                }
        } else if constexpr (PASS == 1) {
            #pragma unroll
            for (int mt = 0; mt < 4; ++mt)
                #pragma unroll
                for (int v = 0; v < 4; ++v) {
                    float s = runRow[mt][v];
                    #pragma unroll
                    for (int nt = 0; nt < 4; ++nt) {
                        float arg = fminf(14.4269504089f,
                                          fmaf(acc[mt][nt][v], a1c[mt][v], a0c[mt][v]));
                        s += exp2f(arg);
                    }
                    runRow[mt][v] = s;
                }
        } else {
            #pragma unroll
            for (int mt = 0; mt < 4; ++mt)
                #pragma unroll
                for (int v = 0; v < 4; ++v) {
                    #pragma unroll
                    for (int nt = 0; nt < 4; ++nt) {
                        float raw = fmaxf(0.f, fmaf(acc[mt][nt][v], -0.5f, 0.5f));
                        float lc = fmaf(-gl4[nt], raw, al4[nt]);
                        runRow[mt][v] = fmaxf(runRow[mt][v], lc);
                    }
                }
        }
    }

    // ---- cross-lane / cross-wave reduction (alias red onto Ab) ----
    __syncthreads();
    float* red = (float*)&Ab[0];
    #pragma unroll
    for (int mt = 0; mt < 4; ++mt)
        #pragma unroll
        for (int v = 0; v < 4; ++v) {
            float val = runRow[mt][v];
            #pragma unroll
            for (int d = 1; d < 16; d <<= 1) {
                float o = __shfl_xor(val, d, 64);
                val = (PASS == 1) ? (val + o) : fmaxf(val, o);
            }
            if (lrow == 0) red[wc * 128 + wr * 64 + mt * 16 + quad * 4 + v] = val;
        }
    __syncthreads();
    if (tid < 128) {
        float a = red[tid], b = red[128 + tid];
        outP[(size_t)(n * NCHUNK + chunk) * SN + ft * 128 + tid] =
            (PASS == 1) ? (a + b) : fmaxf(a, b);
    }
}

// ---------------- small reduce kernels ----------------

__global__ __launch_bounds__(256) void r_g(const float* __restrict__ rowmaxP,
                                           float* __restrict__ grow) {
    int idx = blockIdx.x * 256 + threadIdx.x;
    int n = idx / SN, i = idx - n * SN;
    float m = -3.0e38f;
    for (int ch = 0; ch < NCHUNK; ++ch)
        m = fmaxf(m, rowmaxP[(size_t)(n * NCHUNK + ch) * SN + i]);
    float mr = fmaxf(0.f, (1.f - m) * 0.5f);
    grow[idx] = 10.f / (mr + 1e-5f);
}

__global__ __launch_bounds__(256) void r_alpha(const float* __restrict__ rowsumP,
                                               float* __restrict__ alpha) {
    int idx = blockIdx.x * 256 + threadIdx.x;
    int n = idx / SN, i = idx - n * SN;
    float s = 0.f;
    for (int ch = 0; ch < NCHUNK; ++ch)
        s += rowsumP[(size_t)(n * NCHUNK + ch) * SN + i];
    alpha[idx] = 10.f - logf(s);
}

__global__ __launch_bounds__(256) void r_colfin(const float* __restrict__ colmaxP,
                                                float* __restrict__ bsum) {
    int idx = blockIdx.x * 256 + threadIdx.x;
    int n = idx / SN, j = idx - n * SN;
    float m = -3.0e38f;
    for (int ch = 0; ch < NCHUNK; ++ch)
        m = fmaxf(m, colmaxP[(size_t)(n * NCHUNK + ch) * SN + j]);
    float v = expf(m);
    #pragma unroll
    for (int d = 1; d < 64; d <<= 1) v += __shfl_xor(v, d, 64);
    __shared__ float sb[4];
    if ((threadIdx.x & 63) == 0) sb[threadIdx.x >> 6] = v;
    __syncthreads();
    if (threadIdx.x == 0) bsum[blockIdx.x] = sb[0] + sb[1] + sb[2] + sb[3];
}

__global__ __launch_bounds__(64) void r_loss(const float* __restrict__ bsum,
                                             float* __restrict__ out) {
    int t = threadIdx.x;
    float v = (t < 50) ? bsum[t] : 0.f;
    float v0 = (t < 25) ? v : 0.f;
    float v1 = (t >= 25 && t < 50) ? v : 0.f;
    #pragma unroll
    for (int d = 1; d < 64; d <<= 1) {
        v0 += __shfl_xor(v0, d, 64);
        v1 += __shfl_xor(v1, d, 64);
    }
    if (t == 0) {
        float cs0 = v0 * (1.0f / SN), cs1 = v1 * (1.0f / SN);
        out[0] = -0.5f * (logf(cs0) + logf(cs1));
    }
}

// ---------------- launch ----------------

extern "C" void kernel_launch(void* const* d_in, const int* in_sizes, int n_in,
                              void* d_out, int out_size, void* d_ws, size_t ws_size,
                              hipStream_t stream) {
    const float* I = (const float*)d_in[0];
    const float* T = (const float*)d_in[1];
    float* out = (float*)d_out;

    float* wsf = (float*)d_ws;
    float* meanT = wsf;                        // 256
    float* grow  = meanT + 256;                // 12800
    float* alpha = grow + 12800;               // 12800
    float* rowmaxP = alpha + 12800;            // 128000
    float* rowsumP = rowmaxP + 128000;         // 128000
    float* colmaxP = rowsumP + 128000;         // 128000
    float* bsum = colmaxP + 128000;            // 64
    f16* Ah = (f16*)(bsum + 64);               // 2*6400*256 fp16 (centered I, [n,s,c])
    f16* Bh = Ah + (size_t)NBATCH * SN * CN;   // centered T; total ws ~14.9 MB

    k_meanT<<<256, 256, 0, stream>>>(T, meanT);
    k_xpose<<<dim3(100, 8, 2), 256, 0, stream>>>(I, meanT, Ah);
    k_xpose<<<dim3(100, 8, 2), 256, 0, stream>>>(T, meanT, Bh);
    k_nrm<<<3200, 256, 0, stream>>>(Ah, Bh);

    dim3 gg(NTILES, NCHUNK, NBATCH);
    k_gemm<0><<<gg, 256, 0, stream>>>(Ah, Bh, nullptr, nullptr, rowmaxP);
    r_g<<<50, 256, 0, stream>>>(rowmaxP, grow);
    k_gemm<1><<<gg, 256, 0, stream>>>(Ah, Bh, grow, nullptr, rowsumP);
    r_alpha<<<50, 256, 0, stream>>>(rowsumP, alpha);
    k_gemm<2><<<gg, 256, 0, stream>>>(Bh, Ah, grow, alpha, colmaxP);
    r_colfin<<<50, 256, 0, stream>>>(colmaxP, bsum);
    r_loss<<<1, 64, 0, stream>>>(bsum, out);
}

// Round 5
// 249.426 us; speedup vs baseline: 1.5693x; 1.5693x over previous
//
#include <hip/hip_runtime.h>

#define SN 6400      // H*W
#define CN 256       // channels (= GEMM K)
#define NBATCH 2
#define NTILES 50    // SN / 128
#define NCHUNK 5     // tile chunks per pass (grid = 50*5*2 = 500 blocks, ~2/CU)
#define TPC 10       // tiles per chunk

typedef _Float16 f16;
typedef f16 f16x8 __attribute__((ext_vector_type(8)));
typedef f16 f16x4 __attribute__((ext_vector_type(4)));
typedef float f32x4 __attribute__((ext_vector_type(4)));

__device__ __forceinline__ void gld16(const f16* g, f16* l) {
    __builtin_amdgcn_global_load_lds(
        (__attribute__((address_space(1))) void*)(g),
        (__attribute__((address_space(3))) void*)(l), 16, 0, 0);
}

// Stage a 128-row x 64-half (16 KB) K-chunk into LDS.
// LDS row = 64 halfs = 128 B = 8 x 16B chunks. Chunk at LDS position c holds
// global chunk c ^ (row&7) (swizzle on the SOURCE address; DMA lane->LDS map
// is fixed: wave-uniform base + lane*16B). Verified conflict-free (R2/R3: 0).
__device__ __forceinline__ void stage64(const f16* __restrict__ gbase,
                                        f16* lbase, int tid) {
    #pragma unroll
    for (int it = 0; it < 4; ++it) {
        int q = it * 256 + tid;
        int row = q >> 3, c = q & 7;
        int cg = c ^ (row & 7);
        gld16(gbase + (size_t)row * CN + cg * 8,
              lbase + (size_t)(q & ~63) * 8);
    }
}

// ---------------- prep kernels ----------------

__global__ __launch_bounds__(256) void k_meanT(const float* __restrict__ T,
                                               float* __restrict__ meanT) {
    int c = blockIdx.x, t = threadIdx.x;
    const float* p0 = T + (size_t)c * SN;
    const float* p1 = T + (size_t)(CN + c) * SN;
    float s = 0.f;
    for (int i = t; i < SN; i += 256) s += p0[i] + p1[i];
    #pragma unroll
    for (int d = 1; d < 64; d <<= 1) s += __shfl_xor(s, d, 64);
    __shared__ float sb[4];
    if ((t & 63) == 0) sb[t >> 6] = s;
    __syncthreads();
    if (t == 0) meanT[c] = (sb[0] + sb[1] + sb[2] + sb[3]) * (1.0f / 12800.0f);
}

// transpose [n,c,s] -> [n,s,c], center, cast to fp16 (normalized by k_nrm)
__global__ __launch_bounds__(256) void k_xpose(const float* __restrict__ X,
                                               const float* __restrict__ meanT,
                                               f16* __restrict__ out) {
    int n = blockIdx.z, c0 = blockIdx.y * 32, s0 = blockIdx.x * 64;
    __shared__ float tile[32][65];
    int tx = threadIdx.x & 63, ty = threadIdx.x >> 6;
    const float* Xb = X + ((size_t)n * CN + c0) * SN + s0;
    #pragma unroll
    for (int cy = ty; cy < 32; cy += 4)
        tile[cy][tx] = Xb[(size_t)cy * SN + tx] - meanT[c0 + cy];
    __syncthreads();
    int cc = threadIdx.x & 31, sy = threadIdx.x >> 5;
    f16* ob = out + ((size_t)n * SN + s0) * CN + c0;
    #pragma unroll
    for (int sr = sy; sr < 64; sr += 8)
        ob[(size_t)sr * CN + cc] = (f16)tile[cc][sr];
}

// fused: per-row sum-of-squares -> rsqrt -> in-place scale (one wave per row)
__global__ __launch_bounds__(256) void k_nrm(f16* __restrict__ Ah,
                                             f16* __restrict__ Bh) {
    int w = threadIdx.x >> 6, lane = threadIdx.x & 63;
    int idx = blockIdx.x * 4 + w;
    f16x4* pa = (f16x4*)(Ah + (size_t)idx * CN + lane * 4);
    f16x4* pb = (f16x4*)(Bh + (size_t)idx * CN + lane * 4);
    f16x4 a = *pa, b = *pb;
    float sa = 0.f, sb = 0.f;
    #pragma unroll
    for (int j = 0; j < 4; ++j) {
        float x = (float)a[j]; sa += x * x;
        float y = (float)b[j]; sb += y * y;
    }
    #pragma unroll
    for (int d = 1; d < 64; d <<= 1) {
        sa += __shfl_xor(sa, d, 64);
        sb += __shfl_xor(sb, d, 64);
    }
    float ra = rsqrtf(sa), rb = rsqrtf(sb);
    #pragma unroll
    for (int j = 0; j < 4; ++j) {
        a[j] = (f16)((float)a[j] * ra);
        b[j] = (f16)((float)b[j] * rb);
    }
    *pa = a; *pb = b;
}

// ---------------- fused GEMM passes ----------------
// A-tile (fixed, rows of output) persistent in LDS (64 KB, staged once);
// B loop-tiles staged in 16 KB K-chunks. LDS total 80 KB -> 2 blocks/CU,
// matching the grid-limited residency of the R3 config (grid=500).
// PASS 0: per-row max of cos                          (fixed = I rows i)
// PASS 1: per-row sum of exp((10 - g_i*raw)/ln2)      (fixed = I rows i)
// PASS 2: per-row max over cols of (alpha_c - g_c*raw)(fixed = T rows j)
template <int PASS>
__global__ __launch_bounds__(256, 2) void k_gemm(const f16* __restrict__ A,
                                                 const f16* __restrict__ B,
                                                 const float* __restrict__ grow,
                                                 const float* __restrict__ alpha,
                                                 float* __restrict__ outP) {
    const int n = blockIdx.z, chunk = blockIdx.y, ft = blockIdx.x;
    const int tid = threadIdx.x, lane = tid & 63, wv = tid >> 6;
    const int wr = wv >> 1, wc = wv & 1, quad = lane >> 4, lrow = lane & 15;

    __shared__ f16 Abuf[4][128 * 64];   // 64 KB persistent A tile (h-major)
    __shared__ f16 Bb[128 * 64];        // 16 KB B chunk

    const f16* At = A + ((size_t)n * SN + (size_t)ft * 128) * CN;
    const f16* Lnb = B + (size_t)n * SN * CN;

    // ---- prologue: stage entire A tile once ----
    #pragma unroll
    for (int h = 0; h < 4; ++h) stage64(At + h * 64, Abuf[h], tid);

    // per-lane LDS read offsets (halfs), conflict-free via XOR swizzle
    int offA[4][2], offB[4][2];
    #pragma unroll
    for (int mt = 0; mt < 4; ++mt) {
        int ra = wr * 64 + mt * 16 + lrow;
        int rb = wc * 64 + mt * 16 + lrow;
        #pragma unroll
        for (int kk = 0; kk < 2; ++kk) {
            offA[mt][kk] = ra * 64 + (((kk * 4 + quad) ^ (ra & 7)) * 8);
            offB[mt][kk] = rb * 64 + (((kk * 4 + quad) ^ (rb & 7)) * 8);
        }
    }

    // PASS1 per-row exp coefficients (rows fixed for whole block)
    const float L2E = 1.44269504089f;
    float a0c[4][4], a1c[4][4];
    if constexpr (PASS == 1) {
        #pragma unroll
        for (int mt = 0; mt < 4; ++mt)
            #pragma unroll
            for (int v = 0; v < 4; ++v) {
                int r = ft * 128 + wr * 64 + mt * 16 + quad * 4 + v;
                float gg = grow[(size_t)n * SN + r];
                a1c[mt][v] = 0.5f * gg * L2E;
                a0c[mt][v] = (10.f - 0.5f * gg) * L2E;
            }
    }

    float runRow[4][4];
    #pragma unroll
    for (int mt = 0; mt < 4; ++mt)
        #pragma unroll
        for (int v = 0; v < 4; ++v) runRow[mt][v] = (PASS == 1) ? 0.f : -3.0e38f;

    float gl4[4], al4[4];

    __syncthreads();    // A tile landed (vmcnt drain via barrier)

    for (int t = 0; t < TPC; ++t) {
        const f16* Lt = Lnb + (size_t)(chunk * TPC + t) * 128 * CN;

        if constexpr (PASS == 2) {
            #pragma unroll
            for (int nt = 0; nt < 4; ++nt) {
                int i = (chunk * TPC + t) * 128 + wc * 64 + nt * 16 + lrow;
                gl4[nt] = grow[(size_t)n * SN + i];
                al4[nt] = alpha[(size_t)n * SN + i];
            }
        }

        f32x4 acc[4][4];
        #pragma unroll
        for (int mt = 0; mt < 4; ++mt)
            #pragma unroll
            for (int nt = 0; nt < 4; ++nt) acc[mt][nt] = (f32x4){0.f, 0.f, 0.f, 0.f};

        #pragma unroll 1
        for (int h = 0; h < 4; ++h) {
            __syncthreads();                      // prev stage's Bb reads complete
            stage64(Lt + h * 64, Bb, tid);        // 16 KB DMA
            // preload A fragments for this stage from the persistent buffer —
            // no barrier dependence, overlaps the B DMA
            f16x8 af[2][4];
            #pragma unroll
            for (int kk = 0; kk < 2; ++kk)
                #pragma unroll
                for (int mt = 0; mt < 4; ++mt)
                    af[kk][mt] = *(const f16x8*)&Abuf[h][offA[mt][kk]];
            __syncthreads();                      // B DMA landed
            #pragma unroll
            for (int kk = 0; kk < 2; ++kk) {
                f16x8 bf[4];
                #pragma unroll
                for (int nt = 0; nt < 4; ++nt) bf[nt] = *(const f16x8*)&Bb[offB[nt][kk]];
                #pragma unroll
                for (int mt = 0; mt < 4; ++mt)
                    #pragma unroll
                    for (int nt = 0; nt < 4; ++nt)
                        acc[mt][nt] = __builtin_amdgcn_mfma_f32_16x16x32_f16(
                            af[kk][mt], bf[nt], acc[mt][nt], 0, 0, 0);
            }
        }

        // ---- per-tile epilogue (registers only) ----
        if constexpr (PASS == 0) {
            #pragma unroll
            for (int mt = 0; mt < 4; ++mt)
                #pragma unroll
                for (int v = 0; v < 4; ++v) {
                    float m = fmaxf(fmaxf(acc[mt][0][v], acc[mt][1][v]),
                                    fmaxf(acc[mt][2][v], acc[mt][3][v]));
                    runRow[mt][v] = fmaxf(runRow[mt][v], m);
                }
        } else if constexpr (PASS == 1) {
            #pragma unroll
            for (int mt = 0; mt < 4; ++mt)
                #pragma unroll
                for (int v = 0; v < 4; ++v) {
                    float s = runRow[mt][v];
                    #pragma unroll
                    for (int nt = 0; nt < 4; ++nt) {
                        float arg = fminf(14.4269504089f,
                                          fmaf(acc[mt][nt][v], a1c[mt][v], a0c[mt][v]));
                        s += exp2f(arg);
                    }
                    runRow[mt][v] = s;
                }
        } else {
            #pragma unroll
            for (int mt = 0; mt < 4; ++mt)
                #pragma unroll
                for (int v = 0; v < 4; ++v) {
                    #pragma unroll
                    for (int nt = 0; nt < 4; ++nt) {
                        float raw = fmaxf(0.f, fmaf(acc[mt][nt][v], -0.5f, 0.5f));
                        float lc = fmaf(-gl4[nt], raw, al4[nt]);
                        runRow[mt][v] = fmaxf(runRow[mt][v], lc);
                    }
                }
        }
    }

    // ---- cross-lane / cross-wave reduction (alias red onto Bb) ----
    __syncthreads();
    float* red = (float*)&Bb[0];
    #pragma unroll
    for (int mt = 0; mt < 4; ++mt)
        #pragma unroll
        for (int v = 0; v < 4; ++v) {
            float val = runRow[mt][v];
            #pragma unroll
            for (int d = 1; d < 16; d <<= 1) {
                float o = __shfl_xor(val, d, 64);
                val = (PASS == 1) ? (val + o) : fmaxf(val, o);
            }
            if (lrow == 0) red[wc * 128 + wr * 64 + mt * 16 + quad * 4 + v] = val;
        }
    __syncthreads();
    if (tid < 128) {
        float a = red[tid], b = red[128 + tid];
        outP[(size_t)(n * NCHUNK + chunk) * SN + ft * 128 + tid] =
            (PASS == 1) ? (a + b) : fmaxf(a, b);
    }
}

// ---------------- small reduce kernels ----------------

__global__ __launch_bounds__(256) void r_g(const float* __restrict__ rowmaxP,
                                           float* __restrict__ grow) {
    int idx = blockIdx.x * 256 + threadIdx.x;
    int n = idx / SN, i = idx - n * SN;
    float m = -3.0e38f;
    for (int ch = 0; ch < NCHUNK; ++ch)
        m = fmaxf(m, rowmaxP[(size_t)(n * NCHUNK + ch) * SN + i]);
    float mr = fmaxf(0.f, (1.f - m) * 0.5f);
    grow[idx] = 10.f / (mr + 1e-5f);
}

__global__ __launch_bounds__(256) void r_alpha(const float* __restrict__ rowsumP,
                                               float* __restrict__ alpha) {
    int idx = blockIdx.x * 256 + threadIdx.x;
    int n = idx / SN, i = idx - n * SN;
    float s = 0.f;
    for (int ch = 0; ch < NCHUNK; ++ch)
        s += rowsumP[(size_t)(n * NCHUNK + ch) * SN + i];
    alpha[idx] = 10.f - logf(s);
}

__global__ __launch_bounds__(256) void r_colfin(const float* __restrict__ colmaxP,
                                                float* __restrict__ bsum) {
    int idx = blockIdx.x * 256 + threadIdx.x;
    int n = idx / SN, j = idx - n * SN;
    float m = -3.0e38f;
    for (int ch = 0; ch < NCHUNK; ++ch)
        m = fmaxf(m, colmaxP[(size_t)(n * NCHUNK + ch) * SN + j]);
    float v = expf(m);
    #pragma unroll
    for (int d = 1; d < 64; d <<= 1) v += __shfl_xor(v, d, 64);
    __shared__ float sb[4];
    if ((threadIdx.x & 63) == 0) sb[threadIdx.x >> 6] = v;
    __syncthreads();
    if (threadIdx.x == 0) bsum[blockIdx.x] = sb[0] + sb[1] + sb[2] + sb[3];
}

__global__ __launch_bounds__(64) void r_loss(const float* __restrict__ bsum,
                                             float* __restrict__ out) {
    int t = threadIdx.x;
    float v = (t < 50) ? bsum[t] : 0.f;
    float v0 = (t < 25) ? v : 0.f;
    float v1 = (t >= 25 && t < 50) ? v : 0.f;
    #pragma unroll
    for (int d = 1; d < 64; d <<= 1) {
        v0 += __shfl_xor(v0, d, 64);
        v1 += __shfl_xor(v1, d, 64);
    }
    if (t == 0) {
        float cs0 = v0 * (1.0f / SN), cs1 = v1 * (1.0f / SN);
        out[0] = -0.5f * (logf(cs0) + logf(cs1));
    }
}

// ---------------- launch ----------------

extern "C" void kernel_launch(void* const* d_in, const int* in_sizes, int n_in,
                              void* d_out, int out_size, void* d_ws, size_t ws_size,
                              hipStream_t stream) {
    const float* I = (const float*)d_in[0];
    const float* T = (const float*)d_in[1];
    float* out = (float*)d_out;

    float* wsf = (float*)d_ws;
    float* meanT = wsf;                        // 256
    float* grow  = meanT + 256;                // 12800
    float* alpha = grow + 12800;               // 12800
    float* rowmaxP = alpha + 12800;            // 64000
    float* rowsumP = rowmaxP + 64000;          // 64000
    float* colmaxP = rowsumP + 64000;          // 64000
    float* bsum = colmaxP + 64000;             // 64
    f16* Ah = (f16*)(bsum + 64);               // 2*6400*256 fp16 (centered I, [n,s,c])
    f16* Bh = Ah + (size_t)NBATCH * SN * CN;   // centered T; total ws ~14.1 MB

    k_meanT<<<256, 256, 0, stream>>>(T, meanT);
    k_xpose<<<dim3(100, 8, 2), 256, 0, stream>>>(I, meanT, Ah);
    k_xpose<<<dim3(100, 8, 2), 256, 0, stream>>>(T, meanT, Bh);
    k_nrm<<<3200, 256, 0, stream>>>(Ah, Bh);

    dim3 gg(NTILES, NCHUNK, NBATCH);
    k_gemm<0><<<gg, 256, 0, stream>>>(Ah, Bh, nullptr, nullptr, rowmaxP);
    r_g<<<50, 256, 0, stream>>>(rowmaxP, grow);
    k_gemm<1><<<gg, 256, 0, stream>>>(Ah, Bh, grow, nullptr, rowsumP);
    r_alpha<<<50, 256, 0, stream>>>(rowsumP, alpha);
    k_gemm<2><<<gg, 256, 0, stream>>>(Bh, Ah, grow, alpha, colmaxP);
    r_colfin<<<50, 256, 0, stream>>>(colmaxP, bsum);
    r_loss<<<1, 64, 0, stream>>>(bsum, out);
}